// Round 4
// baseline (4219.342 us; speedup 1.0000x reference)
//
#include <hip/hip_runtime.h>

typedef unsigned short u16;
typedef unsigned int u32;

#define E_TOT 202752   // B*N0*DEG = 32*1584*4
#define NMAX  50688    // B*N0
#define HEADS 4
#define B_    32

#define CDIV(a,b) (((a)+(b)-1)/(b))

// order-preserving float->uint map (monotonic); code 0 is below any real float's code
__device__ __forceinline__ u32 ford(float f) {
  u32 u = __float_as_uint(f);
  return (u & 0x80000000u) ? ~u : (u | 0x80000000u);
}
__device__ __forceinline__ float ford_inv(u32 u) {
  u32 b = (u & 0x80000000u) ? (u ^ 0x80000000u) : ~u;
  return __uint_as_float(b);
}

__global__ void k_edge_init(const int* __restrict__ ei, int* __restrict__ src,
                            int* __restrict__ dst, int* __restrict__ em) {
  int e = blockIdx.x * blockDim.x + threadIdx.x;
  if (e >= E_TOT) return;
  src[e] = ei[e];
  dst[e] = ei[E_TOT + e];
  em[e] = 1;
}

// ---------- per-head node transform: xl_h = h@Wl[:,hoff:hoff+64]+bl[hoff:] ----------
// one block (64 threads = 1 wave) per node
__global__ void k_transform_h(const float* __restrict__ hin, int fin, int hoff,
                              const float* __restrict__ Wl, const float* __restrict__ bl,
                              const float* __restrict__ Wr, const float* __restrict__ br,
                              float* __restrict__ xl, float* __restrict__ xr, int do_xr) {
  __shared__ float xs[64];
  int n = blockIdx.x, j = threadIdx.x;   // 64 threads
  if (j < fin) xs[j] = hin[n * fin + j];
  __syncthreads();
  int col = hoff + j;
  float al = bl[col];
  float ar = do_xr ? br[col] : 0.f;
  for (int i = 0; i < fin; ++i) {
    float xv = xs[i];
    al += xv * Wl[i * 256 + col];
    if (do_xr) ar += xv * Wr[i * 256 + col];
  }
  xl[n * 64 + j] = al;
  if (do_xr) xr[n * 64 + j] = ar;
}

// ---------- per-head edge logits + segment max ----------
__global__ void k_logits_h(const int* __restrict__ src, const int* __restrict__ dst,
                           const int* __restrict__ em, const float* __restrict__ ea,
                           const float* __restrict__ We, const float* __restrict__ att,
                           int hoff, const float* __restrict__ xlh,
                           const float* __restrict__ xrh,
                           float* __restrict__ lg, u32* __restrict__ mxI, int h) {
  int e = blockIdx.x * blockDim.x + threadIdx.x;
  if (e >= E_TOT) return;
  if (!em[e]) { lg[e * 4 + h] = 0.f; return; }
  float eav[8];
#pragma unroll
  for (int d = 0; d < 8; ++d) eav[d] = ea[e * 8 + d];
  const float* xs = xlh + (size_t)src[e] * 64;
  const float* xd = xrh + (size_t)dst[e] * 64;
  float acc = 0.f;
  for (int c = 0; c < 64; ++c) {
    float ee = 0.f;
#pragma unroll
    for (int d = 0; d < 8; ++d) ee += eav[d] * We[d * 256 + hoff + c];
    float m = xs[c] + xd[c] + ee;
    m = (m >= 0.f) ? m : 0.2f * m;   // leaky_relu 0.2
    acc += att[hoff + c] * m;
  }
  lg[e * 4 + h] = acc;
  atomicMax(&mxI[dst[e] * HEADS + h], ford(acc));
}

// decode mx in place: code 0 (no unmasked in-edge) -> 0.0
__global__ void k_mxfin(u32* __restrict__ mxI, int n) {
  int t = blockIdx.x * blockDim.x + threadIdx.x;
  if (t >= n) return;
  u32 u = mxI[t];
  float f = (u == 0u) ? 0.f : ford_inv(u);
  ((float*)mxI)[t] = f;
}

__global__ void k_exp(const int* __restrict__ dst, const int* __restrict__ em,
                      float* __restrict__ lg, const float* __restrict__ mx,
                      float* __restrict__ den) {
  int t = blockIdx.x * blockDim.x + threadIdx.x;
  if (t >= E_TOT * HEADS) return;
  int h = t & 3, e = t >> 2;
  if (!em[e]) { lg[t] = 0.f; return; }
  float ex = expf(lg[t] - mx[dst[e] * HEADS + h]);
  lg[t] = ex;
  atomicAdd(&den[dst[e] * HEADS + h], ex);
}

// alpha = ex/max(den,eps), with the 1/HEADS head-mean folded in
__global__ void k_alpha(const int* __restrict__ dst, const int* __restrict__ em,
                        float* __restrict__ lg, const float* __restrict__ den) {
  int t = blockIdx.x * blockDim.x + threadIdx.x;
  if (t >= E_TOT * HEADS) return;
  int h = t & 3, e = t >> 2;
  if (!em[e]) return;
  lg[t] = 0.25f * lg[t] / fmaxf(den[dst[e] * HEADS + h], 1e-16f);
}

// acc[dst, c] += alpha[e,h] * xlh[src, c]   (per head)
__global__ void k_accum_h(const int* __restrict__ src, const int* __restrict__ dst,
                          const int* __restrict__ em, const float* __restrict__ alpha,
                          const float* __restrict__ xlh, float* __restrict__ acc, int h) {
  int t = blockIdx.x * blockDim.x + threadIdx.x;
  if (t >= E_TOT * 16) return;
  int e = t >> 4, cg = t & 15;
  if (!em[e]) return;
  float a = alpha[e * 4 + h];
  const float* xp = xlh + (size_t)src[e] * 64 + cg * 4;
  float* ap = acc + (size_t)dst[e] * 64 + cg * 4;
  atomicAdd(ap + 0, a * xp[0]);
  atomicAdd(ap + 1, a * xp[1]);
  atomicAdd(ap + 2, a * xp[2]);
  atomicAdd(ap + 3, a * xp[3]);
}

// h = relu(acc + b)  in place  (head-mean already folded into alpha)
__global__ void k_nodeout(float* __restrict__ acc, const float* __restrict__ b, int n64) {
  int t = blockIdx.x * blockDim.x + threadIdx.x;
  if (t >= n64) return;
  float v = acc[t] + b[t & 63];
  acc[t] = fmaxf(v, 0.f);
}

__global__ void k_score(const float* __restrict__ h, const float* __restrict__ w,
                        float* __restrict__ s, int N) {
  int t = blockIdx.x * blockDim.x + threadIdx.x;
  if (t >= N) return;
  float dot = 0.f, wn = 0.f;
  for (int c = 0; c < 64; ++c) {
    float wv = w[c];
    dot += h[(size_t)t * 64 + c] * wv;
    wn += wv * wv;
  }
  s[t] = tanhf(dot / sqrtf(wn));
}

// stable descending sort per graph (bitonic on <=2048 padded), emit perm + new_id
__global__ __launch_bounds__(1024) void k_topk(const float* __restrict__ s, int n_per,
                                               int k, int npad,
                                               int* __restrict__ perm, int* __restrict__ new_id) {
  __shared__ float sv[2048];
  __shared__ int si[2048];
  int b = blockIdx.x, tid = threadIdx.x;
  int base = b * n_per;
  for (int i = tid; i < n_per; i += 1024) new_id[base + i] = -1;
  for (int i = tid; i < npad; i += 1024) {
    if (i < n_per) { sv[i] = s[base + i]; si[i] = i; }
    else { sv[i] = -INFINITY; si[i] = i; }   // idx >= n_per sinks ties
  }
  __syncthreads();
  for (int kk = 2; kk <= npad; kk <<= 1) {
    for (int j = kk >> 1; j > 0; j >>= 1) {
      for (int i = tid; i < npad; i += 1024) {
        int ixj = i ^ j;
        if (ixj > i) {
          float sa = sv[i], sb = sv[ixj];
          int ia = si[i], ib = si[ixj];
          // "a belongs after b" in (score desc, idx asc) order
          bool after = (sa < sb) || (sa == sb && ia > ib);
          bool doswap = ((i & kk) == 0) ? after : !after;
          if (doswap) { sv[i] = sb; sv[ixj] = sa; si[i] = ib; si[ixj] = ia; }
        }
      }
      __syncthreads();
    }
  }
  for (int r = tid; r < k; r += 1024) {
    int old = si[r];
    perm[b * k + r] = base + old;
    new_id[base + old] = b * k + r;
  }
}

__global__ void k_gather(const float* __restrict__ hin, const float* __restrict__ s,
                         const int* __restrict__ perm, float* __restrict__ hout, int n64) {
  int t = blockIdx.x * blockDim.x + threadIdx.x;
  if (t >= n64) return;
  int i = t >> 6, c = t & 63;
  int g = perm[i];
  hout[t] = hin[(size_t)g * 64 + c] * s[g];
}

__global__ void k_remap(int* __restrict__ src, int* __restrict__ dst,
                        int* __restrict__ em, const int* __restrict__ new_id) {
  int e = blockIdx.x * blockDim.x + threadIdx.x;
  if (e >= E_TOT) return;
  int ns = new_id[src[e]], nd = new_id[dst[e]];
  int m = em[e] && ns >= 0 && nd >= 0;
  src[e] = m ? ns : 0;
  dst[e] = m ? nd : 0;
  em[e] = m;
}

// r[b, 0:64] += mean over k nodes ; r[b, 64:128] += max over k nodes
__global__ void k_readout(const float* __restrict__ h, int k, float* __restrict__ r) {
  int b = blockIdx.x, c = threadIdx.x;   // 128 threads
  const float* hb = h + (size_t)b * k * 64;
  if (c < 64) {
    float sum = 0.f;
    for (int i = 0; i < k; ++i) sum += hb[(size_t)i * 64 + c];
    r[b * 128 + c] += sum / (float)k;
  } else {
    int cc = c - 64;
    float m = -INFINITY;
    for (int i = 0; i < k; ++i) m = fmaxf(m, hb[(size_t)i * 64 + cc]);
    r[b * 128 + c] += m;
  }
}

__global__ void k_mlp(const float* __restrict__ r,
                      const float* __restrict__ W1, const float* __restrict__ b1,
                      const float* __restrict__ W2, const float* __restrict__ b2,
                      const float* __restrict__ W3, const float* __restrict__ b3,
                      float* __restrict__ out) {
  __shared__ float v0[128], v1[64], v2[64], lgts[16];
  int b = blockIdx.x, t = threadIdx.x;   // 64 threads
  v0[t] = r[b * 128 + t];
  v0[64 + t] = r[b * 128 + 64 + t];
  __syncthreads();
  float a = b1[t];
  for (int i = 0; i < 128; ++i) a += v0[i] * W1[i * 64 + t];
  v1[t] = fmaxf(a, 0.f);
  __syncthreads();
  a = b2[t];
  for (int i = 0; i < 64; ++i) a += v1[i] * W2[i * 64 + t];
  v2[t] = fmaxf(a, 0.f);
  __syncthreads();
  if (t < 16) {
    a = b3[t];
    for (int i = 0; i < 64; ++i) a += v2[i] * W3[i * 16 + t];
    lgts[t] = a;
  }
  __syncthreads();
  if (t == 0) {
    float m = lgts[0];
    for (int j = 1; j < 16; ++j) m = fmaxf(m, lgts[j]);
    float ex[16], sum = 0.f;
    for (int j = 0; j < 16; ++j) { ex[j] = expf(lgts[j] - m); sum += ex[j]; }
    for (int j = 0; j < 16; ++j) out[b * 16 + j] = ex[j] / sum;   // f32 output
  }
}

extern "C" void kernel_launch(void* const* d_in, const int* in_sizes, int n_in,
                              void* d_out, int out_size, void* d_ws, size_t ws_size,
                              hipStream_t stream) {
  (void)in_sizes; (void)n_in; (void)out_size; (void)ws_size;
  const float* x  = (const float*)d_in[0];      // [NMAX, 32] f32
  const float* ea = (const float*)d_in[1];      // [E, 8]     f32
  const int*   ei = (const int*)d_in[2];        // [2, E]
  // d_in[3] = batch (unused; layout is static)

  const float *gWl[3], *gbl[3], *gWr[3], *gbr[3], *gWe[3], *gatt[3], *gb[3], *pw[3];
  for (int l = 0; l < 3; ++l) {
    int p0 = 4 + 7 * l;
    gWl[l]  = (const float*)d_in[p0 + 0];
    gbl[l]  = (const float*)d_in[p0 + 1];
    gWr[l]  = (const float*)d_in[p0 + 2];
    gbr[l]  = (const float*)d_in[p0 + 3];
    gWe[l]  = (const float*)d_in[p0 + 4];
    gatt[l] = (const float*)d_in[p0 + 5];
    gb[l]   = (const float*)d_in[p0 + 6];
    pw[l]   = (const float*)d_in[25 + l];
  }
  const float* fc1W = (const float*)d_in[28];
  const float* fc1b = (const float*)d_in[29];
  const float* fc2W = (const float*)d_in[30];
  const float* fc2b = (const float*)d_in[31];
  const float* fc3W = (const float*)d_in[32];
  const float* fc3b = (const float*)d_in[33];

  // ---- workspace carve (~47 MB) ----
  char* w = (char*)d_ws;
  size_t off = 0;
  auto alloc = [&](size_t bytes) -> void* {
    void* p = w + off;
    off += (bytes + 255) & ~(size_t)255;
    return p;
  };
  float* hbuf = (float*)alloc((size_t)NMAX * 64 * 4);   // pooled layer input
  float* xlh  = (float*)alloc((size_t)NMAX * 64 * 4);   // per-head source transform
  float* xra  = (float*)alloc((size_t)NMAX * 64 * 4);   // per-head target transform, then acc
  float* lg   = (float*)alloc((size_t)E_TOT * 4 * 4);   // logits -> exp -> alpha
  char*  mhd  = (char*)alloc((size_t)NMAX * 8 * 4);     // [mxI NMAX*4 u32][den NMAX*4 f32]
  u32*   mxI  = (u32*)mhd;
  float* den  = (float*)(mhd + (size_t)NMAX * 4 * 4);
  float* sbuf = (float*)alloc((size_t)NMAX * 4);
  float* rbuf = (float*)alloc(32 * 128 * 4);
  int* src    = (int*)alloc((size_t)E_TOT * 4);
  int* dst    = (int*)alloc((size_t)E_TOT * 4);
  int* em     = (int*)alloc((size_t)E_TOT * 4);
  int* new_id = (int*)alloc((size_t)NMAX * 4);
  int* perm   = (int*)alloc((size_t)32 * 1268 * 4);

  k_edge_init<<<CDIV(E_TOT, 256), 256, 0, stream>>>(ei, src, dst, em);
  hipMemsetAsync(rbuf, 0, 32 * 128 * 4, stream);

  const int Ns[3]    = {50688, 40576, 32480};   // B*N0, B*K1, B*K2
  const int npers[3] = {1584, 1268, 1015};
  const int ks[3]    = {1268, 1015, 812};
  const int npads[3] = {2048, 2048, 1024};

  for (int l = 0; l < 3; ++l) {
    int N = Ns[l];
    int fin = (l == 0) ? 32 : 64;
    const float* hin = (l == 0) ? x : hbuf;
    hipMemsetAsync(mhd, 0, (size_t)NMAX * 8 * 4, stream);   // full region (fixed offsets)
    // logits pass, head by head
    for (int h = 0; h < HEADS; ++h) {
      k_transform_h<<<N, 64, 0, stream>>>(hin, fin, h * 64, gWl[l], gbl[l],
                                          gWr[l], gbr[l], xlh, xra, 1);
      k_logits_h<<<CDIV(E_TOT, 256), 256, 0, stream>>>(src, dst, em, ea, gWe[l],
                                                       gatt[l], h * 64, xlh, xra,
                                                       lg, mxI, h);
    }
    k_mxfin<<<CDIV(N * 4, 256), 256, 0, stream>>>(mxI, N * 4);
    k_exp<<<CDIV(E_TOT * 4, 256), 256, 0, stream>>>(dst, em, lg, (const float*)mxI, den);
    k_alpha<<<CDIV(E_TOT * 4, 256), 256, 0, stream>>>(dst, em, lg, den);
    // aggregation pass, head by head (xra becomes acc)
    hipMemsetAsync(xra, 0, (size_t)N * 64 * 4, stream);
    for (int h = 0; h < HEADS; ++h) {
      k_transform_h<<<N, 64, 0, stream>>>(hin, fin, h * 64, gWl[l], gbl[l],
                                          gWr[l], gbr[l], xlh, nullptr, 0);
      k_accum_h<<<CDIV(E_TOT * 16, 256), 256, 0, stream>>>(src, dst, em, lg, xlh, xra, h);
    }
    k_nodeout<<<CDIV(N * 64, 256), 256, 0, stream>>>(xra, gb[l], N * 64);
    k_score<<<CDIV(N, 256), 256, 0, stream>>>(xra, pw[l], sbuf, N);
    k_topk<<<32, 1024, 0, stream>>>(sbuf, npers[l], ks[l], npads[l], perm, new_id);
    k_gather<<<CDIV(B_ * ks[l] * 64, 256), 256, 0, stream>>>(xra, sbuf, perm, hbuf,
                                                             B_ * ks[l] * 64);
    k_remap<<<CDIV(E_TOT, 256), 256, 0, stream>>>(src, dst, em, new_id);
    k_readout<<<32, 128, 0, stream>>>(hbuf, ks[l], rbuf);
  }
  k_mlp<<<32, 64, 0, stream>>>(rbuf, fc1W, fc1b, fc2W, fc2b, fc3W, fc3b, (float*)d_out);
}

// Round 5
// 1954.254 us; speedup vs baseline: 2.1591x; 2.1591x over previous
//
#include <hip/hip_runtime.h>

typedef unsigned short u16;
typedef unsigned int u32;

#define E_TOT 202752   // B*N0*DEG = 32*1584*4
#define NMAX  50688    // B*N0
#define HEADS 4
#define B_    32

#define CDIV(a,b) (((a)+(b)-1)/(b))

// order-preserving float->uint map (monotonic); code 0 is below any real float's code
__device__ __forceinline__ u32 ford(float f) {
  u32 u = __float_as_uint(f);
  return (u & 0x80000000u) ? ~u : (u | 0x80000000u);
}
__device__ __forceinline__ float ford_inv(u32 u) {
  u32 b = (u & 0x80000000u) ? (u ^ 0x80000000u) : ~u;
  return __uint_as_float(b);
}

__global__ void k_edge_init(const int* __restrict__ ei, int* __restrict__ src,
                            int* __restrict__ dst, int* __restrict__ em) {
  int e = blockIdx.x * blockDim.x + threadIdx.x;
  if (e >= E_TOT) return;
  src[e] = ei[e];
  dst[e] = ei[E_TOT + e];
  em[e] = 1;
}

// ================= fused-head path =================
// xl/xr full [N,256]; one block (256 thr) per node
__global__ void k_transform256(const float* __restrict__ hin, int fin,
                               const float* __restrict__ Wl, const float* __restrict__ bl,
                               const float* __restrict__ Wr, const float* __restrict__ br,
                               float* __restrict__ xl, float* __restrict__ xr) {
  __shared__ float xs[64];
  int n = blockIdx.x, j = threadIdx.x;   // 256 threads
  if (j < fin) xs[j] = hin[n * fin + j];
  __syncthreads();
  float al = bl[j], ar = br[j];
  for (int i = 0; i < fin; ++i) {
    float xv = xs[i];
    al += xv * Wl[i * 256 + j];
    ar += xv * Wr[i * 256 + j];
  }
  xl[(size_t)n * 256 + j] = al;
  xr[(size_t)n * 256 + j] = ar;
}

// all heads in one launch: blockIdx.y = h
__global__ void k_logits4(const int* __restrict__ src, const int* __restrict__ dst,
                          const int* __restrict__ em, const float* __restrict__ ea,
                          const float* __restrict__ We, const float* __restrict__ att,
                          const float* __restrict__ xl, const float* __restrict__ xr,
                          float* __restrict__ lg, u32* __restrict__ mxI) {
  int e = blockIdx.x * blockDim.x + threadIdx.x;
  int h = blockIdx.y, hoff = h * 64;
  if (e >= E_TOT) return;
  if (!em[e]) { lg[e * 4 + h] = 0.f; return; }
  float eav[8];
#pragma unroll
  for (int d = 0; d < 8; ++d) eav[d] = ea[e * 8 + d];
  const float* xs = xl + (size_t)src[e] * 256 + hoff;
  const float* xd = xr + (size_t)dst[e] * 256 + hoff;
  float acc = 0.f;
  for (int c = 0; c < 64; ++c) {
    float ee = 0.f;
#pragma unroll
    for (int d = 0; d < 8; ++d) ee += eav[d] * We[d * 256 + hoff + c];
    float m = xs[c] + xd[c] + ee;
    m = (m >= 0.f) ? m : 0.2f * m;   // leaky_relu 0.2
    acc += att[hoff + c] * m;
  }
  lg[e * 4 + h] = acc;
  atomicMax(&mxI[dst[e] * HEADS + h], ford(acc));
}

// exp with inline ford-decode of the max (code 0 = no in-edge -> mx 0)
__global__ void k_exp(const int* __restrict__ dst, const int* __restrict__ em,
                      float* __restrict__ lg, const u32* __restrict__ mxI,
                      float* __restrict__ den) {
  int t = blockIdx.x * blockDim.x + threadIdx.x;
  if (t >= E_TOT * HEADS) return;
  int h = t & 3, e = t >> 2;
  if (!em[e]) { lg[t] = 0.f; return; }
  u32 u = mxI[dst[e] * HEADS + h];
  float mx = (u == 0u) ? 0.f : ford_inv(u);
  float ex = expf(lg[t] - mx);
  lg[t] = ex;
  atomicAdd(&den[dst[e] * HEADS + h], ex);
}

// fused alpha + head-summed accumulation: acc[dst,c] += sum_h 0.25*ex/den * xl[src,h,c]
__global__ void k_accum4(const int* __restrict__ src, const int* __restrict__ dst,
                         const int* __restrict__ em, const float* __restrict__ lg,
                         const float* __restrict__ den, const float* __restrict__ xl,
                         float* __restrict__ acc) {
  int t = blockIdx.x * blockDim.x + threadIdx.x;
  if (t >= E_TOT * 16) return;
  int e = t >> 4, cg = t & 15;
  if (!em[e]) return;
  int sn = src[e], dn = dst[e];
  float s0 = 0.f, s1 = 0.f, s2 = 0.f, s3 = 0.f;
#pragma unroll
  for (int h = 0; h < 4; ++h) {
    float a = 0.25f * lg[e * 4 + h] / fmaxf(den[dn * 4 + h], 1e-16f);
    const float* xp = xl + (size_t)sn * 256 + h * 64 + cg * 4;
    s0 += a * xp[0]; s1 += a * xp[1]; s2 += a * xp[2]; s3 += a * xp[3];
  }
  float* ap = acc + (size_t)dn * 64 + cg * 4;
  atomicAdd(ap + 0, s0); atomicAdd(ap + 1, s1);
  atomicAdd(ap + 2, s2); atomicAdd(ap + 3, s3);
}

// ================= per-head fallback path =================
__global__ void k_transform_h(const float* __restrict__ hin, int fin, int hoff,
                              const float* __restrict__ Wl, const float* __restrict__ bl,
                              const float* __restrict__ Wr, const float* __restrict__ br,
                              float* __restrict__ xl, float* __restrict__ xr, int do_xr) {
  __shared__ float xs[64];
  int n = blockIdx.x, j = threadIdx.x;   // 64 threads
  if (j < fin) xs[j] = hin[n * fin + j];
  __syncthreads();
  int col = hoff + j;
  float al = bl[col];
  float ar = do_xr ? br[col] : 0.f;
  for (int i = 0; i < fin; ++i) {
    float xv = xs[i];
    al += xv * Wl[i * 256 + col];
    if (do_xr) ar += xv * Wr[i * 256 + col];
  }
  xl[n * 64 + j] = al;
  if (do_xr) xr[n * 64 + j] = ar;
}

__global__ void k_logits_h(const int* __restrict__ src, const int* __restrict__ dst,
                           const int* __restrict__ em, const float* __restrict__ ea,
                           const float* __restrict__ We, const float* __restrict__ att,
                           int hoff, const float* __restrict__ xlh,
                           const float* __restrict__ xrh,
                           float* __restrict__ lg, u32* __restrict__ mxI, int h) {
  int e = blockIdx.x * blockDim.x + threadIdx.x;
  if (e >= E_TOT) return;
  if (!em[e]) { lg[e * 4 + h] = 0.f; return; }
  float eav[8];
#pragma unroll
  for (int d = 0; d < 8; ++d) eav[d] = ea[e * 8 + d];
  const float* xs = xlh + (size_t)src[e] * 64;
  const float* xd = xrh + (size_t)dst[e] * 64;
  float acc = 0.f;
  for (int c = 0; c < 64; ++c) {
    float ee = 0.f;
#pragma unroll
    for (int d = 0; d < 8; ++d) ee += eav[d] * We[d * 256 + hoff + c];
    float m = xs[c] + xd[c] + ee;
    m = (m >= 0.f) ? m : 0.2f * m;
    acc += att[hoff + c] * m;
  }
  lg[e * 4 + h] = acc;
  atomicMax(&mxI[dst[e] * HEADS + h], ford(acc));
}

__global__ void k_alpha(const int* __restrict__ dst, const int* __restrict__ em,
                        float* __restrict__ lg, const float* __restrict__ den) {
  int t = blockIdx.x * blockDim.x + threadIdx.x;
  if (t >= E_TOT * HEADS) return;
  int h = t & 3, e = t >> 2;
  if (!em[e]) return;
  lg[t] = 0.25f * lg[t] / fmaxf(den[dst[e] * HEADS + h], 1e-16f);
}

__global__ void k_accum_h(const int* __restrict__ src, const int* __restrict__ dst,
                          const int* __restrict__ em, const float* __restrict__ alpha,
                          const float* __restrict__ xlh, float* __restrict__ acc, int h) {
  int t = blockIdx.x * blockDim.x + threadIdx.x;
  if (t >= E_TOT * 16) return;
  int e = t >> 4, cg = t & 15;
  if (!em[e]) return;
  float a = alpha[e * 4 + h];
  const float* xp = xlh + (size_t)src[e] * 64 + cg * 4;
  float* ap = acc + (size_t)dst[e] * 64 + cg * 4;
  atomicAdd(ap + 0, a * xp[0]);
  atomicAdd(ap + 1, a * xp[1]);
  atomicAdd(ap + 2, a * xp[2]);
  atomicAdd(ap + 3, a * xp[3]);
}

// ================= shared tail =================
// relu(acc+b) in place, then topk score s = tanh(h.w/||w||)
__global__ void k_nodeout_score(float* __restrict__ acc, const float* __restrict__ b,
                                const float* __restrict__ w, float* __restrict__ s, int N) {
  int n = blockIdx.x * blockDim.x + threadIdx.x;
  if (n >= N) return;
  float dot = 0.f, wn = 0.f;
  float* row = acc + (size_t)n * 64;
  for (int c = 0; c < 64; ++c) {
    float v = fmaxf(row[c] + b[c], 0.f);
    row[c] = v;
    float wv = w[c];
    dot += v * wv;
    wn += wv * wv;
  }
  s[n] = tanhf(dot / sqrtf(wn));
}

// stable descending sort per graph (bitonic on <=2048 padded), emit perm + new_id
__global__ __launch_bounds__(1024) void k_topk(const float* __restrict__ s, int n_per,
                                               int k, int npad,
                                               int* __restrict__ perm, int* __restrict__ new_id) {
  __shared__ float sv[2048];
  __shared__ int si[2048];
  int b = blockIdx.x, tid = threadIdx.x;
  int base = b * n_per;
  for (int i = tid; i < n_per; i += 1024) new_id[base + i] = -1;
  for (int i = tid; i < npad; i += 1024) {
    if (i < n_per) { sv[i] = s[base + i]; si[i] = i; }
    else { sv[i] = -INFINITY; si[i] = i; }
  }
  __syncthreads();
  for (int kk = 2; kk <= npad; kk <<= 1) {
    for (int j = kk >> 1; j > 0; j >>= 1) {
      for (int i = tid; i < npad; i += 1024) {
        int ixj = i ^ j;
        if (ixj > i) {
          float sa = sv[i], sb = sv[ixj];
          int ia = si[i], ib = si[ixj];
          bool after = (sa < sb) || (sa == sb && ia > ib);
          bool doswap = ((i & kk) == 0) ? after : !after;
          if (doswap) { sv[i] = sb; sv[ixj] = sa; si[i] = ib; si[ixj] = ia; }
        }
      }
      __syncthreads();
    }
  }
  for (int r = tid; r < k; r += 1024) {
    int old = si[r];
    perm[b * k + r] = base + old;
    new_id[base + old] = b * k + r;
  }
}

__global__ void k_gather(const float* __restrict__ hin, const float* __restrict__ s,
                         const int* __restrict__ perm, float* __restrict__ hout, int n64) {
  int t = blockIdx.x * blockDim.x + threadIdx.x;
  if (t >= n64) return;
  int i = t >> 6, c = t & 63;
  int g = perm[i];
  hout[t] = hin[(size_t)g * 64 + c] * s[g];
}

__global__ void k_remap(int* __restrict__ src, int* __restrict__ dst,
                        int* __restrict__ em, const int* __restrict__ new_id) {
  int e = blockIdx.x * blockDim.x + threadIdx.x;
  if (e >= E_TOT) return;
  int ns = new_id[src[e]], nd = new_id[dst[e]];
  int m = em[e] && ns >= 0 && nd >= 0;
  src[e] = m ? ns : 0;
  dst[e] = m ? nd : 0;
  em[e] = m;
}

// chunked parallel readout: grid (B, 16), 256 thr; partial sum/max per column -> atomics
__global__ void k_readout_part(const float* __restrict__ h, int k,
                               float* __restrict__ rsum, u32* __restrict__ rmaxI) {
  __shared__ float ps[256], pm[256];
  int b = blockIdx.x, ch = blockIdx.y, t = threadIdx.x;
  int c = t & 63, rg = t >> 6;                 // 4 row-groups
  int rpc = (k + 15) >> 4;
  int start = ch * rpc, end = min(k, start + rpc);
  const float* hb = h + (size_t)b * k * 64;
  float sum = 0.f, mx = -INFINITY;
  for (int i = start + rg; i < end; i += 4) {
    float v = hb[(size_t)i * 64 + c];
    sum += v;
    mx = fmaxf(mx, v);
  }
  ps[t] = sum; pm[t] = mx;
  __syncthreads();
  if (t < 64) {
    float s4 = ps[t] + ps[t + 64] + ps[t + 128] + ps[t + 192];
    float m4 = fmaxf(fmaxf(pm[t], pm[t + 64]), fmaxf(pm[t + 128], pm[t + 192]));
    atomicAdd(&rsum[b * 64 + t], s4);
    atomicMax(&rmaxI[b * 64 + t], ford(m4));
  }
}

__global__ void k_readout_fin(const float* __restrict__ rsum, const u32* __restrict__ rmaxI,
                              int k, float* __restrict__ r) {
  int b = blockIdx.x, c = threadIdx.x;   // 128 threads
  if (c < 64) r[b * 128 + c] += rsum[b * 64 + c] / (float)k;
  else        r[b * 128 + c] += ford_inv(rmaxI[b * 64 + (c - 64)]);
}

__global__ void k_mlp(const float* __restrict__ r,
                      const float* __restrict__ W1, const float* __restrict__ b1,
                      const float* __restrict__ W2, const float* __restrict__ b2,
                      const float* __restrict__ W3, const float* __restrict__ b3,
                      float* __restrict__ out) {
  __shared__ float v0[128], v1[64], v2[64], lgts[16];
  int b = blockIdx.x, t = threadIdx.x;   // 64 threads
  v0[t] = r[b * 128 + t];
  v0[64 + t] = r[b * 128 + 64 + t];
  __syncthreads();
  float a = b1[t];
  for (int i = 0; i < 128; ++i) a += v0[i] * W1[i * 64 + t];
  v1[t] = fmaxf(a, 0.f);
  __syncthreads();
  a = b2[t];
  for (int i = 0; i < 64; ++i) a += v1[i] * W2[i * 64 + t];
  v2[t] = fmaxf(a, 0.f);
  __syncthreads();
  if (t < 16) {
    a = b3[t];
    for (int i = 0; i < 64; ++i) a += v2[i] * W3[i * 16 + t];
    lgts[t] = a;
  }
  __syncthreads();
  if (t == 0) {
    float m = lgts[0];
    for (int j = 1; j < 16; ++j) m = fmaxf(m, lgts[j]);
    float ex[16], sum = 0.f;
    for (int j = 0; j < 16; ++j) { ex[j] = expf(lgts[j] - m); sum += ex[j]; }
    for (int j = 0; j < 16; ++j) out[b * 16 + j] = ex[j] / sum;
  }
}

extern "C" void kernel_launch(void* const* d_in, const int* in_sizes, int n_in,
                              void* d_out, int out_size, void* d_ws, size_t ws_size,
                              hipStream_t stream) {
  (void)in_sizes; (void)n_in; (void)out_size;
  const float* x  = (const float*)d_in[0];      // [NMAX, 32] f32
  const float* ea = (const float*)d_in[1];      // [E, 8]     f32
  const int*   ei = (const int*)d_in[2];        // [2, E]

  const float *gWl[3], *gbl[3], *gWr[3], *gbr[3], *gWe[3], *gatt[3], *gb[3], *pw[3];
  for (int l = 0; l < 3; ++l) {
    int p0 = 4 + 7 * l;
    gWl[l]  = (const float*)d_in[p0 + 0];
    gbl[l]  = (const float*)d_in[p0 + 1];
    gWr[l]  = (const float*)d_in[p0 + 2];
    gbr[l]  = (const float*)d_in[p0 + 3];
    gWe[l]  = (const float*)d_in[p0 + 4];
    gatt[l] = (const float*)d_in[p0 + 5];
    gb[l]   = (const float*)d_in[p0 + 6];
    pw[l]   = (const float*)d_in[25 + l];
  }
  const float* fc1W = (const float*)d_in[28];
  const float* fc1b = (const float*)d_in[29];
  const float* fc2W = (const float*)d_in[30];
  const float* fc2b = (const float*)d_in[31];
  const float* fc3W = (const float*)d_in[32];
  const float* fc3b = (const float*)d_in[33];

  // fused path needs ~125.5 MB; fallback ~47 MB
  const bool fused = ws_size >= ((size_t)132 << 20);

  char* w = (char*)d_ws;
  size_t off = 0;
  auto alloc = [&](size_t bytes) -> void* {
    void* p = w + off;
    off += (bytes + 255) & ~(size_t)255;
    return p;
  };
  size_t xwide = fused ? 256 : 64;
  float* hbuf = (float*)alloc((size_t)NMAX * 64 * 4);     // pooled layer input
  float* xl   = (float*)alloc((size_t)NMAX * xwide * 4);  // source transform
  float* xr   = (float*)alloc((size_t)NMAX * xwide * 4);  // target transform; acc reuses it
  float* lg   = (float*)alloc((size_t)E_TOT * 4 * 4);     // logits -> exp(-> alpha fallback)
  // zeroed-per-layer block: [mxI][den][rsum][rmaxI]
  char*  zblk = (char*)alloc((size_t)NMAX * 8 * 4 + 32 * 128 * 4);
  u32*   mxI  = (u32*)zblk;
  float* den  = (float*)(zblk + (size_t)NMAX * 4 * 4);
  float* rsum = (float*)(zblk + (size_t)NMAX * 8 * 4);
  u32*   rmaxI= (u32*)(zblk + (size_t)NMAX * 8 * 4 + 32 * 64 * 4);
  size_t zbytes = (size_t)NMAX * 8 * 4 + 32 * 128 * 4;
  float* sbuf = (float*)alloc((size_t)NMAX * 4);
  float* rbuf = (float*)alloc(32 * 128 * 4);
  int* src    = (int*)alloc((size_t)E_TOT * 4);
  int* dst    = (int*)alloc((size_t)E_TOT * 4);
  int* em     = (int*)alloc((size_t)E_TOT * 4);
  int* new_id = (int*)alloc((size_t)NMAX * 4);
  int* perm   = (int*)alloc((size_t)32 * 1268 * 4);

  k_edge_init<<<CDIV(E_TOT, 256), 256, 0, stream>>>(ei, src, dst, em);
  hipMemsetAsync(rbuf, 0, 32 * 128 * 4, stream);

  const int Ns[3]    = {50688, 40576, 32480};   // B*N0, B*K1, B*K2
  const int npers[3] = {1584, 1268, 1015};
  const int ks[3]    = {1268, 1015, 812};
  const int npads[3] = {2048, 2048, 1024};

  for (int l = 0; l < 3; ++l) {
    int N = Ns[l];
    int fin = (l == 0) ? 32 : 64;
    const float* hin = (l == 0) ? x : hbuf;
    hipMemsetAsync(zblk, 0, zbytes, stream);
    float* acc;
    if (fused) {
      k_transform256<<<N, 256, 0, stream>>>(hin, fin, gWl[l], gbl[l], gWr[l], gbr[l], xl, xr);
      k_logits4<<<dim3(CDIV(E_TOT, 256), 4), 256, 0, stream>>>(src, dst, em, ea, gWe[l],
                                                               gatt[l], xl, xr, lg, mxI);
      k_exp<<<CDIV(E_TOT * 4, 256), 256, 0, stream>>>(dst, em, lg, mxI, den);
      acc = xr;   // xr dead after logits; reuse as accumulator
      hipMemsetAsync(acc, 0, (size_t)N * 64 * 4, stream);
      k_accum4<<<CDIV(E_TOT * 16, 256), 256, 0, stream>>>(src, dst, em, lg, den, xl, acc);
    } else {
      for (int h = 0; h < HEADS; ++h) {
        k_transform_h<<<N, 64, 0, stream>>>(hin, fin, h * 64, gWl[l], gbl[l],
                                            gWr[l], gbr[l], xl, xr, 1);
        k_logits_h<<<CDIV(E_TOT, 256), 256, 0, stream>>>(src, dst, em, ea, gWe[l],
                                                         gatt[l], h * 64, xl, xr,
                                                         lg, mxI, h);
      }
      k_exp<<<CDIV(E_TOT * 4, 256), 256, 0, stream>>>(dst, em, lg, mxI, den);
      k_alpha<<<CDIV(E_TOT * 4, 256), 256, 0, stream>>>(dst, em, lg, den);
      acc = xr;
      hipMemsetAsync(acc, 0, (size_t)N * 64 * 4, stream);
      for (int h = 0; h < HEADS; ++h) {
        k_transform_h<<<N, 64, 0, stream>>>(hin, fin, h * 64, gWl[l], gbl[l],
                                            gWr[l], gbr[l], xl, nullptr, 0);
        k_accum_h<<<CDIV(E_TOT * 16, 256), 256, 0, stream>>>(src, dst, em, lg, xl, acc, h);
      }
    }
    k_nodeout_score<<<CDIV(N, 256), 256, 0, stream>>>(acc, gb[l], pw[l], sbuf, N);
    k_topk<<<32, 1024, 0, stream>>>(sbuf, npers[l], ks[l], npads[l], perm, new_id);
    k_gather<<<CDIV(B_ * ks[l] * 64, 256), 256, 0, stream>>>(acc, sbuf, perm, hbuf,
                                                             B_ * ks[l] * 64);
    k_remap<<<CDIV(E_TOT, 256), 256, 0, stream>>>(src, dst, em, new_id);
    k_readout_part<<<dim3(32, 16), 256, 0, stream>>>(hbuf, ks[l], rsum, rmaxI);
    k_readout_fin<<<32, 128, 0, stream>>>(rsum, rmaxI, ks[l], rbuf);
  }
  k_mlp<<<32, 64, 0, stream>>>(rbuf, fc1W, fc1b, fc2W, fc2b, fc3W, fc3b, (float*)d_out);
}

// Round 6
// 861.733 us; speedup vs baseline: 4.8963x; 2.2678x over previous
//
#include <hip/hip_runtime.h>

typedef unsigned short u16;
typedef unsigned int u32;

#define E_TOT 202752   // B*N0*DEG = 32*1584*4
#define NMAX  50688    // B*N0
#define HEADS 4
#define B_    32

#define CDIV(a,b) (((a)+(b)-1)/(b))

// order-preserving float->uint map (monotonic); code 0 is below any real float's code
__device__ __forceinline__ u32 ford(float f) {
  u32 u = __float_as_uint(f);
  return (u & 0x80000000u) ? ~u : (u | 0x80000000u);
}
__device__ __forceinline__ float ford_inv(u32 u) {
  u32 b = (u & 0x80000000u) ? (u ^ 0x80000000u) : ~u;
  return __uint_as_float(b);
}

__global__ void k_edge_init(const int* __restrict__ ei, int* __restrict__ src,
                            int* __restrict__ dst, int* __restrict__ em) {
  int e = blockIdx.x * blockDim.x + threadIdx.x;
  if (e >= E_TOT) return;
  src[e] = ei[e];
  dst[e] = ei[E_TOT + e];
  em[e] = 1;
}

// ---------- node transform, 8 nodes/block, W columns reused in regs ----------
template <int FIN>
__global__ void k_transform_t(const float* __restrict__ hin,
                              const float* __restrict__ Wl, const float* __restrict__ bl,
                              const float* __restrict__ Wr, const float* __restrict__ br,
                              float* __restrict__ xl, float* __restrict__ xr) {
  __shared__ float xs[8][FIN];
  int n0 = blockIdx.x * 8, j = threadIdx.x;   // 256 threads
  for (int t = j; t < 8 * FIN; t += 256)
    xs[t >> (FIN == 32 ? 5 : 6)][t & (FIN - 1)] =
        hin[(size_t)(n0 + (t >> (FIN == 32 ? 5 : 6))) * FIN + (t & (FIN - 1))];
  __syncthreads();
  float al[8], ar[8];
  float blv = bl[j], brv = br[j];
#pragma unroll
  for (int t = 0; t < 8; ++t) { al[t] = blv; ar[t] = brv; }
  for (int i = 0; i < FIN; ++i) {
    float wl = Wl[i * 256 + j], wr = Wr[i * 256 + j];
#pragma unroll
    for (int t = 0; t < 8; ++t) {
      float xv = xs[t][i];
      al[t] += xv * wl;
      ar[t] += xv * wr;
    }
  }
#pragma unroll
  for (int t = 0; t < 8; ++t) {
    xl[(size_t)(n0 + t) * 256 + j] = al[t];
    xr[(size_t)(n0 + t) * 256 + j] = ar[t];
  }
}

// ---------- wave-per-edge logits: lane = channel, coalesced row loads ----------
__global__ void k_logits_w(const int* __restrict__ src, const int* __restrict__ dst,
                           const int* __restrict__ em, const float* __restrict__ ea,
                           const float* __restrict__ We, const float* __restrict__ att,
                           const float* __restrict__ xl, const float* __restrict__ xr,
                           float* __restrict__ lg, u32* __restrict__ mxI) {
  int e = blockIdx.x * 4 + (threadIdx.x >> 6);   // 4 waves/block, 1 edge/wave
  int lane = threadIdx.x & 63;
  if (e >= E_TOT) return;
  if (!em[e]) { if (lane < 4) lg[e * 4 + lane] = 0.f; return; }
  float eav[8];
#pragma unroll
  for (int d = 0; d < 8; ++d) eav[d] = ea[e * 8 + d];   // same addr all lanes: broadcast
  const float* xs = xl + (size_t)src[e] * 256;
  const float* xd = xr + (size_t)dst[e] * 256;
  int dn = dst[e];
#pragma unroll
  for (int h = 0; h < 4; ++h) {
    int c = h * 64 + lane;                                // 64-lane contiguous: coalesced
    float ee = 0.f;
#pragma unroll
    for (int d = 0; d < 8; ++d) ee += eav[d] * We[d * 256 + c];
    float m = xs[c] + xd[c] + ee;
    m = (m >= 0.f) ? m : 0.2f * m;                        // leaky_relu 0.2
    float v = att[c] * m;
#pragma unroll
    for (int s = 1; s < 64; s <<= 1) v += __shfl_xor(v, s, 64);
    if (lane == 0) {
      lg[e * 4 + h] = v;
      atomicMax(&mxI[dn * 4 + h], ford(v));
    }
  }
}

// exp with inline ford-decode of the max (code 0 = no in-edge -> mx 0)
__global__ void k_exp(const int* __restrict__ dst, const int* __restrict__ em,
                      float* __restrict__ lg, const u32* __restrict__ mxI,
                      float* __restrict__ den) {
  int t = blockIdx.x * blockDim.x + threadIdx.x;
  if (t >= E_TOT * HEADS) return;
  int h = t & 3, e = t >> 2;
  if (!em[e]) { lg[t] = 0.f; return; }
  u32 u = mxI[dst[e] * HEADS + h];
  float mx = (u == 0u) ? 0.f : ford_inv(u);
  float ex = expf(lg[t] - mx);
  lg[t] = ex;
  atomicAdd(&den[dst[e] * HEADS + h], ex);
}

// ---------- wave-per-edge accumulation: lane = channel ----------
// acc[dst, c] += sum_h 0.25*ex/den * xl[src, h*64+c]
__global__ void k_accum_w(const int* __restrict__ src, const int* __restrict__ dst,
                          const int* __restrict__ em, const float* __restrict__ lg,
                          const float* __restrict__ den, const float* __restrict__ xl,
                          float* __restrict__ acc) {
  int e = blockIdx.x * 4 + (threadIdx.x >> 6);
  int lane = threadIdx.x & 63;
  if (e >= E_TOT || !em[e]) return;
  int sn = src[e], dn = dst[e];
  const float* xp = xl + (size_t)sn * 256;
  float s = 0.f;
#pragma unroll
  for (int h = 0; h < 4; ++h) {
    float a = 0.25f * lg[e * 4 + h] / fmaxf(den[dn * 4 + h], 1e-16f);  // broadcast loads
    s += a * xp[h * 64 + lane];                                        // coalesced
  }
  atomicAdd(&acc[(size_t)dn * 64 + lane], s);                          // coalesced row
}

// relu(acc+b) in place, then topk score s = tanh(h.w/||w||)
__global__ void k_nodeout_score(float* __restrict__ acc, const float* __restrict__ b,
                                const float* __restrict__ w, float* __restrict__ s, int N) {
  int n = blockIdx.x * blockDim.x + threadIdx.x;
  if (n >= N) return;
  float dot = 0.f, wn = 0.f;
  float* row = acc + (size_t)n * 64;
  for (int c = 0; c < 64; ++c) {
    float v = fmaxf(row[c] + b[c], 0.f);
    row[c] = v;
    float wv = w[c];
    dot += v * wv;
    wn += wv * wv;
  }
  s[n] = tanhf(dot / sqrtf(wn));
}

// stable descending sort per graph (bitonic on <=2048 padded), emit perm + new_id
__global__ __launch_bounds__(1024) void k_topk(const float* __restrict__ s, int n_per,
                                               int k, int npad,
                                               int* __restrict__ perm, int* __restrict__ new_id) {
  __shared__ float sv[2048];
  __shared__ int si[2048];
  int b = blockIdx.x, tid = threadIdx.x;
  int base = b * n_per;
  for (int i = tid; i < n_per; i += 1024) new_id[base + i] = -1;
  for (int i = tid; i < npad; i += 1024) {
    if (i < n_per) { sv[i] = s[base + i]; si[i] = i; }
    else { sv[i] = -INFINITY; si[i] = i; }
  }
  __syncthreads();
  for (int kk = 2; kk <= npad; kk <<= 1) {
    for (int j = kk >> 1; j > 0; j >>= 1) {
      for (int i = tid; i < npad; i += 1024) {
        int ixj = i ^ j;
        if (ixj > i) {
          float sa = sv[i], sb = sv[ixj];
          int ia = si[i], ib = si[ixj];
          bool after = (sa < sb) || (sa == sb && ia > ib);
          bool doswap = ((i & kk) == 0) ? after : !after;
          if (doswap) { sv[i] = sb; sv[ixj] = sa; si[i] = ib; si[ixj] = ia; }
        }
      }
      __syncthreads();
    }
  }
  for (int r = tid; r < k; r += 1024) {
    int old = si[r];
    perm[b * k + r] = base + old;
    new_id[base + old] = b * k + r;
  }
}

__global__ void k_gather(const float* __restrict__ hin, const float* __restrict__ s,
                         const int* __restrict__ perm, float* __restrict__ hout, int n64) {
  int t = blockIdx.x * blockDim.x + threadIdx.x;
  if (t >= n64) return;
  int i = t >> 6, c = t & 63;
  int g = perm[i];
  hout[t] = hin[(size_t)g * 64 + c] * s[g];
}

__global__ void k_remap(int* __restrict__ src, int* __restrict__ dst,
                        int* __restrict__ em, const int* __restrict__ new_id) {
  int e = blockIdx.x * blockDim.x + threadIdx.x;
  if (e >= E_TOT) return;
  int ns = new_id[src[e]], nd = new_id[dst[e]];
  int m = em[e] && ns >= 0 && nd >= 0;
  src[e] = m ? ns : 0;
  dst[e] = m ? nd : 0;
  em[e] = m;
}

// chunked parallel readout: grid (B, 16), 256 thr
__global__ void k_readout_part(const float* __restrict__ h, int k,
                               float* __restrict__ rsum, u32* __restrict__ rmaxI) {
  __shared__ float ps[256], pm[256];
  int b = blockIdx.x, ch = blockIdx.y, t = threadIdx.x;
  int c = t & 63, rg = t >> 6;
  int rpc = (k + 15) >> 4;
  int start = ch * rpc, end = min(k, start + rpc);
  const float* hb = h + (size_t)b * k * 64;
  float sum = 0.f, mx = -INFINITY;
  for (int i = start + rg; i < end; i += 4) {
    float v = hb[(size_t)i * 64 + c];
    sum += v;
    mx = fmaxf(mx, v);
  }
  ps[t] = sum; pm[t] = mx;
  __syncthreads();
  if (t < 64) {
    float s4 = ps[t] + ps[t + 64] + ps[t + 128] + ps[t + 192];
    float m4 = fmaxf(fmaxf(pm[t], pm[t + 64]), fmaxf(pm[t + 128], pm[t + 192]));
    atomicAdd(&rsum[b * 64 + t], s4);
    atomicMax(&rmaxI[b * 64 + t], ford(m4));
  }
}

__global__ void k_readout_fin(const float* __restrict__ rsum, const u32* __restrict__ rmaxI,
                              int k, float* __restrict__ r) {
  int b = blockIdx.x, c = threadIdx.x;   // 128 threads
  if (c < 64) r[b * 128 + c] += rsum[b * 64 + c] / (float)k;
  else        r[b * 128 + c] += ford_inv(rmaxI[b * 64 + (c - 64)]);
}

__global__ void k_mlp(const float* __restrict__ r,
                      const float* __restrict__ W1, const float* __restrict__ b1,
                      const float* __restrict__ W2, const float* __restrict__ b2,
                      const float* __restrict__ W3, const float* __restrict__ b3,
                      float* __restrict__ out) {
  __shared__ float v0[128], v1[64], v2[64], lgts[16];
  int b = blockIdx.x, t = threadIdx.x;   // 64 threads
  v0[t] = r[b * 128 + t];
  v0[64 + t] = r[b * 128 + 64 + t];
  __syncthreads();
  float a = b1[t];
  for (int i = 0; i < 128; ++i) a += v0[i] * W1[i * 64 + t];
  v1[t] = fmaxf(a, 0.f);
  __syncthreads();
  a = b2[t];
  for (int i = 0; i < 64; ++i) a += v1[i] * W2[i * 64 + t];
  v2[t] = fmaxf(a, 0.f);
  __syncthreads();
  if (t < 16) {
    a = b3[t];
    for (int i = 0; i < 64; ++i) a += v2[i] * W3[i * 16 + t];
    lgts[t] = a;
  }
  __syncthreads();
  if (t == 0) {
    float m = lgts[0];
    for (int j = 1; j < 16; ++j) m = fmaxf(m, lgts[j]);
    float ex[16], sum = 0.f;
    for (int j = 0; j < 16; ++j) { ex[j] = expf(lgts[j] - m); sum += ex[j]; }
    for (int j = 0; j < 16; ++j) out[b * 16 + j] = ex[j] / sum;
  }
}

extern "C" void kernel_launch(void* const* d_in, const int* in_sizes, int n_in,
                              void* d_out, int out_size, void* d_ws, size_t ws_size,
                              hipStream_t stream) {
  (void)in_sizes; (void)n_in; (void)out_size; (void)ws_size;
  const float* x  = (const float*)d_in[0];      // [NMAX, 32] f32
  const float* ea = (const float*)d_in[1];      // [E, 8]     f32
  const int*   ei = (const int*)d_in[2];        // [2, E]

  const float *gWl[3], *gbl[3], *gWr[3], *gbr[3], *gWe[3], *gatt[3], *gb[3], *pw[3];
  for (int l = 0; l < 3; ++l) {
    int p0 = 4 + 7 * l;
    gWl[l]  = (const float*)d_in[p0 + 0];
    gbl[l]  = (const float*)d_in[p0 + 1];
    gWr[l]  = (const float*)d_in[p0 + 2];
    gbr[l]  = (const float*)d_in[p0 + 3];
    gWe[l]  = (const float*)d_in[p0 + 4];
    gatt[l] = (const float*)d_in[p0 + 5];
    gb[l]   = (const float*)d_in[p0 + 6];
    pw[l]   = (const float*)d_in[25 + l];
  }
  const float* fc1W = (const float*)d_in[28];
  const float* fc1b = (const float*)d_in[29];
  const float* fc2W = (const float*)d_in[30];
  const float* fc2b = (const float*)d_in[31];
  const float* fc3W = (const float*)d_in[32];
  const float* fc3b = (const float*)d_in[33];

  // ---- workspace carve (~125.5 MB; ws proven >= this by round-5 fused run) ----
  char* w = (char*)d_ws;
  size_t off = 0;
  auto alloc = [&](size_t bytes) -> void* {
    void* p = w + off;
    off += (bytes + 255) & ~(size_t)255;
    return p;
  };
  float* hbuf = (float*)alloc((size_t)NMAX * 64 * 4);     // pooled layer input
  float* xl   = (float*)alloc((size_t)NMAX * 256 * 4);    // source transform [N,256]
  float* xr   = (float*)alloc((size_t)NMAX * 256 * 4);    // target transform; acc reuses it
  float* lg   = (float*)alloc((size_t)E_TOT * 4 * 4);     // logits -> exp
  char*  zblk = (char*)alloc((size_t)NMAX * 8 * 4 + 32 * 128 * 4);  // zeroed per layer
  u32*   mxI  = (u32*)zblk;
  float* den  = (float*)(zblk + (size_t)NMAX * 4 * 4);
  float* rsum = (float*)(zblk + (size_t)NMAX * 8 * 4);
  u32*   rmaxI= (u32*)(zblk + (size_t)NMAX * 8 * 4 + 32 * 64 * 4);
  size_t zbytes = (size_t)NMAX * 8 * 4 + 32 * 128 * 4;
  float* sbuf = (float*)alloc((size_t)NMAX * 4);
  float* rbuf = (float*)alloc(32 * 128 * 4);
  int* src    = (int*)alloc((size_t)E_TOT * 4);
  int* dst    = (int*)alloc((size_t)E_TOT * 4);
  int* em     = (int*)alloc((size_t)E_TOT * 4);
  int* new_id = (int*)alloc((size_t)NMAX * 4);
  int* perm   = (int*)alloc((size_t)32 * 1268 * 4);

  k_edge_init<<<CDIV(E_TOT, 256), 256, 0, stream>>>(ei, src, dst, em);
  hipMemsetAsync(rbuf, 0, 32 * 128 * 4, stream);

  const int Ns[3]    = {50688, 40576, 32480};   // B*N0, B*K1, B*K2 (all %8==0)
  const int npers[3] = {1584, 1268, 1015};
  const int ks[3]    = {1268, 1015, 812};
  const int npads[3] = {2048, 2048, 1024};

  for (int l = 0; l < 3; ++l) {
    int N = Ns[l];
    const float* hin = (l == 0) ? x : hbuf;
    hipMemsetAsync(zblk, 0, zbytes, stream);
    if (l == 0)
      k_transform_t<32><<<N / 8, 256, 0, stream>>>(hin, gWl[l], gbl[l], gWr[l], gbr[l], xl, xr);
    else
      k_transform_t<64><<<N / 8, 256, 0, stream>>>(hin, gWl[l], gbl[l], gWr[l], gbr[l], xl, xr);
    k_logits_w<<<CDIV(E_TOT, 4), 256, 0, stream>>>(src, dst, em, ea, gWe[l], gatt[l],
                                                   xl, xr, lg, mxI);
    k_exp<<<CDIV(E_TOT * 4, 256), 256, 0, stream>>>(dst, em, lg, mxI, den);
    float* acc = xr;   // xr dead after logits; reuse as accumulator
    hipMemsetAsync(acc, 0, (size_t)N * 64 * 4, stream);
    k_accum_w<<<CDIV(E_TOT, 4), 256, 0, stream>>>(src, dst, em, lg, den, xl, acc);
    k_nodeout_score<<<CDIV(N, 256), 256, 0, stream>>>(acc, gb[l], pw[l], sbuf, N);
    k_topk<<<32, 1024, 0, stream>>>(sbuf, npers[l], ks[l], npads[l], perm, new_id);
    k_gather<<<CDIV(B_ * ks[l] * 64, 256), 256, 0, stream>>>(acc, sbuf, perm, hbuf,
                                                             B_ * ks[l] * 64);
    k_remap<<<CDIV(E_TOT, 256), 256, 0, stream>>>(src, dst, em, new_id);
    k_readout_part<<<dim3(32, 16), 256, 0, stream>>>(hbuf, ks[l], rsum, rmaxI);
    k_readout_fin<<<32, 128, 0, stream>>>(rsum, rmaxI, ks[l], rbuf);
  }
  k_mlp<<<32, 64, 0, stream>>>(rbuf, fc1W, fc1b, fc2W, fc2b, fc3W, fc3b, (float*)d_out);
}